// Round 25
// baseline (232.402 us; speedup 1.0000x reference)
//
#include <hip/hip_runtime.h>
#include <cstdint>
#include <cstddef>

constexpr int NN = 50000;
constexpr int NE = 800000;

typedef _Float16 half8 __attribute__((ext_vector_type(8)));
typedef _Float16 half4v __attribute__((ext_vector_type(4)));
typedef _Float16 half2v __attribute__((ext_vector_type(2)));
typedef float f32x16 __attribute__((ext_vector_type(16)));
typedef unsigned short ushort_t;

__device__ inline ushort_t f2h(float f) {
  _Float16 h = (_Float16)f;
  return __builtin_bit_cast(ushort_t, h);
}

#if __has_builtin(__builtin_amdgcn_fdot2)
__device__ inline float fdot2(half2v a, half2v b, float c) {
  return __builtin_amdgcn_fdot2(a, b, c, false);
}
#else
__device__ inline float fdot2(half2v a, half2v b, float c) {
  return c + (float)a[0] * (float)b[0] + (float)a[1] * (float)b[1];
}
#endif

// ---- FAT KERNEL A: weight pre-transform (blocks 0..915) + degrank (rest) -----
constexpr int WCONV_BLOCKS = (234496 + 255) / 256;          // 916
constexpr int DEGRANK_BLOCKS = (NE + 255) / 256;            // 3125
__global__ __launch_bounds__(256) void k_preA(const float* __restrict__ Wp,
    const float* __restrict__ Wl1, const float* __restrict__ Wr1,
    const float* __restrict__ Wl2, const float* __restrict__ Wr2,
    const float* __restrict__ W1, const float* __restrict__ W2,
    ushort_t* __restrict__ wb, const int* __restrict__ ei,
    int* __restrict__ deg, int* __restrict__ rank)
{
  if (blockIdx.x < WCONV_BLOCKS) {
    int idx = blockIdx.x * 256 + threadIdx.x;
    if (idx >= 234496) return;
    const float* W;
    int M, K, base, li;
    if (idx < 131072)      { W = Wp;  M = 256; K = 512; base = 0;      li = idx; }
    else if (idx < 163840) { W = Wl1; M = 128; K = 256; base = 131072; li = idx - 131072; }
    else if (idx < 196608) { W = Wr1; M = 128; K = 256; base = 163840; li = idx - 163840; }
    else if (idx < 212992) { W = Wl2; M = 128; K = 128; base = 196608; li = idx - 196608; }
    else if (idx < 229376) { W = Wr2; M = 128; K = 128; base = 212992; li = idx - 212992; }
    else if (idx < 233472) { W = W1;  M = 32;  K = 128; base = 229376; li = idx - 229376; }
    else                   { W = W2;  M = 10;  K = 32;  base = 233472; li = idx - 233472; }
    int j = li & 7;
    int l = (li >> 3) & 63;
    int blk = li >> 9;
    int nKB = K >> 4;
    int cb = blk / nKB, kb = blk - cb * nKB;
    int col = cb * 32 + (l & 31);
    int k = kb * 16 + ((l >> 5) & 1) * 8 + j;
    float v = (col < M) ? W[(size_t)col * K + k] : 0.f;
    wb[base + li] = f2h(v);
  } else {
    int e = (blockIdx.x - WCONV_BLOCKS) * 256 + threadIdx.x;
    if (e >= NE) return;
    int d = ei[NE + e];
    rank[e] = atomicAdd(&deg[d], 1);
  }
}

// ---- FAT KERNEL B: mega1 (proj+L1 GEMM, blocks 0..GX-1) + scatter (rest) -----
constexpr int GX = (NN + 63) / 64;                          // 782
constexpr int SCAT_BLOCKS = (NE + 511) / 512;               // 1563
__global__ __launch_bounds__(512) void k_mainB(const float* __restrict__ x,
    const ushort_t* __restrict__ WpF, const ushort_t* __restrict__ WB1,
    const float* __restrict__ bp, const float* __restrict__ bl1,
    const float* __restrict__ br1, ushort_t* __restrict__ xlh,
    ushort_t* __restrict__ xrh, int N,
    const int* __restrict__ ei, const int* __restrict__ rowst,
    const int* __restrict__ rank, int* __restrict__ srcp)
{
  constexpr int NKK = 4;            // BKT=64
  constexpr int nKB1 = 32;          // K1=512
  constexpr int nK1 = 8;
  __shared__ ushort_t Ah[2][2 * NKK * 512];
  __shared__ ushort_t H0[16384];

  if (blockIdx.x >= GX) {
    int e = (blockIdx.x - GX) * 512 + threadIdx.x;
    if (e < NE) {
      int d = ei[NE + e];
      srcp[rowst[d] + rank[e]] = ei[e];
    }
    return;
  }

  const int t = threadIdx.x;
  const int lane = t & 63;
  const int wid = t >> 6;
  const int wr = wid >> 2;
  const int wc = wid & 3;
  const int row0 = blockIdx.x * 64;
  const int cb0 = wc * 2;

  const int s_r = t >> 4, s_k = (t & 15) * 4;
  const int sb0 = (s_k >> 4) * 512 + (s_r + 32 * ((s_k >> 3) & 1)) * 8 + (s_k & 7);
  const int sb1 = sb0 + NKK * 512;
  const bool ok0 = (row0 + s_r) < N;
  const bool ok1 = (row0 + s_r + 32) < N;
  const float* ap0 = x + (size_t)(row0 + s_r) * 512 + s_k;
  const float* ap1 = x + (size_t)(row0 + s_r + 32) * 512 + s_k;

  f32x16 acc0 = {}, acc1 = {};
  float4 f0 = make_float4(0, 0, 0, 0), f1 = make_float4(0, 0, 0, 0);

  auto aload = [&](int ks) {
    f0 = make_float4(0, 0, 0, 0);
    f1 = make_float4(0, 0, 0, 0);
    if (ok0) f0 = *(const float4*)(ap0 + (size_t)ks * 64);
    if (ok1) f1 = *(const float4*)(ap1 + (size_t)ks * 64);
  };
  auto cvt4 = [](float4 f) {
    half4v h;
    h[0] = (_Float16)f.x; h[1] = (_Float16)f.y;
    h[2] = (_Float16)f.z; h[3] = (_Float16)f.w;
    return h;
  };
  auto stage_write = [&](int buf) {
    *(half4v*)&Ah[buf][sb0] = cvt4(f0);
    *(half4v*)&Ah[buf][sb1] = cvt4(f1);
  };

  aload(0);
  stage_write(0);
  __syncthreads();

  for (int ks = 0; ks < nK1; ++ks) {
    const int cur = ks & 1;
    const int nxt = cur ^ 1;
    const bool have_next = (ks + 1 < nK1);
    if (have_next) aload(ks + 1);

    #pragma unroll
    for (int kk = 0; kk < NKK; ++kk) {
      const int kbg = ks * NKK + kk;
      half8 ah = *(const half8*)&Ah[cur][(wr * NKK + kk) * 512 + lane * 8];
      const size_t bo0 = ((size_t)(cb0 * nKB1 + kbg) * 64 + lane) * 8;
      half8 bh0 = *(const half8*)(WpF + bo0);
      acc0 = __builtin_amdgcn_mfma_f32_32x32x16_f16(ah, bh0, acc0, 0, 0, 0);
      const size_t bo1 = ((size_t)((cb0 + 1) * nKB1 + kbg) * 64 + lane) * 8;
      half8 bh1 = *(const half8*)(WpF + bo1);
      acc1 = __builtin_amdgcn_mfma_f32_32x32x16_f16(ah, bh1, acc1, 0, 0, 0);
    }

    if (have_next) stage_write(nxt);
    __syncthreads();
  }

  {
    int col = cb0 * 32 + (lane & 31);
    float bv = bp[col];
    #pragma unroll
    for (int r = 0; r < 16; ++r) {
      int row = wr * 32 + (r & 3) + 8 * (r >> 2) + 4 * (lane >> 5);
      float v = acc0[r] + bv;
      v = v > 0.f ? v : (__expf(v) - 1.f);
      H0[((row >> 5) * 16 + (col >> 4)) * 512 +
         ((row & 31) + 32 * ((col >> 3) & 1)) * 8 + (col & 7)] = f2h(v);
    }
    int col1 = col + 32;
    float bv1 = bp[col1];
    #pragma unroll
    for (int r = 0; r < 16; ++r) {
      int row = wr * 32 + (r & 3) + 8 * (r >> 2) + 4 * (lane >> 5);
      float v = acc1[r] + bv1;
      v = v > 0.f ? v : (__expf(v) - 1.f);
      H0[((row >> 5) * 16 + (col1 >> 4)) * 512 +
         ((row & 31) + 32 * ((col1 >> 3) & 1)) * 8 + (col1 & 7)] = f2h(v);
    }
  }
  __syncthreads();

  f32x16 acc2a = {}, acc2b = {};
  #pragma unroll
  for (int kk = 0; kk < 16; ++kk) {
    half8 ah = *(const half8*)&H0[(wr * 16 + kk) * 512 + lane * 8];
    const size_t bo0 = ((size_t)(cb0 * 16 + kk) * 64 + lane) * 8;
    half8 bh0 = *(const half8*)(WB1 + bo0);
    acc2a = __builtin_amdgcn_mfma_f32_32x32x16_f16(ah, bh0, acc2a, 0, 0, 0);
    const size_t bo1 = ((size_t)((cb0 + 1) * 16 + kk) * 64 + lane) * 8;
    half8 bh1 = *(const half8*)(WB1 + bo1);
    acc2b = __builtin_amdgcn_mfma_f32_32x32x16_f16(ah, bh1, acc2b, 0, 0, 0);
  }

  auto epi2 = [&](const f32x16& acc, int cb) {
    int cc = cb * 32 + (lane & 31);
    float bv = (cc < 128) ? bl1[cc] : br1[cc - 128];
    #pragma unroll
    for (int r = 0; r < 16; ++r) {
      int rr = row0 + wr * 32 + (r & 3) + 8 * (r >> 2) + 4 * (lane >> 5);
      if (rr < N) {
        float v = acc[r] + bv;
        if (cc < 128) xlh[(size_t)rr * 128 + cc] = f2h(v);
        else          xrh[(size_t)rr * 128 + (cc - 128)] = f2h(v);
      }
    }
  };
  epi2(acc2a, cb0);
  epi2(acc2b, cb0 + 1);
}

// ---- MEGAKERNEL 2: MLP1 (K=128 -> h3 tile in LDS) + MLP2 (K=32 -> out) -------
__global__ __launch_bounds__(512) void gemm_mlp(const ushort_t* __restrict__ h2,
    const ushort_t* __restrict__ W1F, const ushort_t* __restrict__ W2F,
    const float* __restrict__ b1, const float* __restrict__ b2,
    float* __restrict__ out, int N)
{
  constexpr int NKK = 4;
  __shared__ ushort_t Ah[2][2 * NKK * 512];
  __shared__ ushort_t H3[2048];
  const int t = threadIdx.x;
  const int lane = t & 63;
  const int wid = t >> 6;
  const int wr = wid >> 2;
  const int wc = wid & 3;
  const int row0 = blockIdx.x * 64;

  const int s_r = t >> 3, s_k = (t & 7) * 8;
  const int sb0 = ((s_r >> 5) * NKK + (s_k >> 4)) * 512 +
                  ((s_r & 31) + 32 * ((s_k >> 3) & 1)) * 8;
  const bool ok0 = (row0 + s_r) < N;
  const ushort_t* aph = h2 + (size_t)(row0 + s_r) * 128 + s_k;

  f32x16 acc = {};
  half8 h8 = {};

  auto aload = [&](int ks) {
    half8 z = {};
    h8 = ok0 ? *(const half8*)(aph + (size_t)ks * 64) : z;
  };

  aload(0);
  *(half8*)&Ah[0][sb0] = h8;
  __syncthreads();

  for (int ks = 0; ks < 2; ++ks) {
    const int cur = ks & 1;
    const bool have_next = (ks == 0);
    if (have_next) aload(1);

    if (wc == 0) {
      #pragma unroll
      for (int kk = 0; kk < NKK; ++kk) {
        const int kbg = ks * NKK + kk;
        half8 ah = *(const half8*)&Ah[cur][(wr * NKK + kk) * 512 + lane * 8];
        half8 bh = *(const half8*)(W1F + ((size_t)kbg * 64 + lane) * 8);
        acc = __builtin_amdgcn_mfma_f32_32x32x16_f16(ah, bh, acc, 0, 0, 0);
      }
    }

    if (have_next) *(half8*)&Ah[cur ^ 1][sb0] = h8;
    __syncthreads();
  }

  if (wc == 0) {
    int cc = lane & 31;
    float bv = b1[cc];
    #pragma unroll
    for (int r = 0; r < 16; ++r) {
      int row = wr * 32 + (r & 3) + 8 * (r >> 2) + 4 * (lane >> 5);
      float v = acc[r] + bv;
      v = v > 0.f ? v : (__expf(v) - 1.f);
      H3[((row >> 5) * 2 + (cc >> 4)) * 512 +
         ((row & 31) + 32 * ((cc >> 3) & 1)) * 8 + (cc & 7)] = f2h(v);
    }
  }
  __syncthreads();

  if (wc == 0) {
    f32x16 acc2 = {};
    #pragma unroll
    for (int kk = 0; kk < 2; ++kk) {
      half8 ah = *(const half8*)&H3[(wr * 2 + kk) * 512 + lane * 8];
      half8 bh = *(const half8*)(W2F + ((size_t)kk * 64 + lane) * 8);
      acc2 = __builtin_amdgcn_mfma_f32_32x32x16_f16(ah, bh, acc2, 0, 0, 0);
    }
    int cc = lane & 31;
    if (cc < 10) {
      float bv = b2[cc];
      #pragma unroll
      for (int r = 0; r < 16; ++r) {
        int rr = row0 + wr * 32 + (r & 3) + 8 * (r >> 2) + 4 * (lane >> 5);
        if (rr < N) out[(size_t)rr * 10 + cc] = acc2[r] + bv;
      }
    }
  }
}

// ---- fp16 MFMA GEMM (r17 body) for the L2 fused layer ------------------------
template<int ACT, int OUTMODE, int BKT, int AFP16, int NCB>
__global__ __launch_bounds__(512) void gemm_mfma(const void* __restrict__ Av,
    const ushort_t* __restrict__ Bh,
    const float* __restrict__ bias, const float* __restrict__ bias2,
    float* __restrict__ C, ushort_t* __restrict__ C16a,
    ushort_t* __restrict__ C16b, int N, int M, int K)
{
  constexpr int NKK = BKT / 16;
  __shared__ ushort_t Ah[2][2 * NKK * 512];
  const int t = threadIdx.x;
  const int lane = t & 63;
  const int wid = t >> 6;
  const int wr = wid >> 2;
  const int wc = wid & 3;
  const int row0 = blockIdx.x * 64;
  const int col0 = blockIdx.y * (128 * NCB);
  const int nKB = K >> 4;
  const int nK = K / BKT;
  const int cb0 = (col0 >> 5) + wc * NCB;

  int s_r, s_k, sb0, sb1 = 0;
  bool ok0 = false, ok1 = false;
  if constexpr (!AFP16) {
    s_r = t >> 4; s_k = (t & 15) * 4;
    sb0 = (s_k >> 4) * 512 + (s_r + 32 * ((s_k >> 3) & 1)) * 8 + (s_k & 7);
    sb1 = sb0 + NKK * 512;
    ok0 = (row0 + s_r) < N;
    ok1 = (row0 + s_r + 32) < N;
  } else if constexpr (BKT == 64) {
    s_r = t >> 3; s_k = (t & 7) * 8;
    sb0 = ((s_r >> 5) * NKK + (s_k >> 4)) * 512 +
          ((s_r & 31) + 32 * ((s_k >> 3) & 1)) * 8;
    ok0 = (row0 + s_r) < N;
  } else {
    s_r = t >> 3; s_k = (t & 7) * 4;
    sb0 = ((s_r >> 5) * NKK + (s_k >> 4)) * 512 +
          ((s_r & 31) + 32 * ((s_k >> 3) & 1)) * 8 + (s_k & 7);
    ok0 = (row0 + s_r) < N;
  }
  const float*    ap0 = (const float*)Av + (size_t)(row0 + s_r) * K + s_k;
  const float*    ap1 = (const float*)Av + (size_t)(row0 + s_r + 32) * K + s_k;
  const ushort_t* aph = (const ushort_t*)Av + (size_t)(row0 + s_r) * K + s_k;

  f32x16 acc0 = {}, acc1 = {};
  float4 f0 = make_float4(0, 0, 0, 0), f1 = make_float4(0, 0, 0, 0);
  half8 h8 = {};
  half4v h4 = {};

  auto aload = [&](int ks) {
    if constexpr (!AFP16) {
      f0 = make_float4(0, 0, 0, 0);
      f1 = make_float4(0, 0, 0, 0);
      if (ok0) f0 = *(const float4*)(ap0 + (size_t)ks * BKT);
      if (ok1) f1 = *(const float4*)(ap1 + (size_t)ks * BKT);
    } else if constexpr (BKT == 64) {
      half8 z = {};
      h8 = ok0 ? *(const half8*)(aph + (size_t)ks * BKT) : z;
    } else {
      half4v z = {};
      h4 = ok0 ? *(const half4v*)(aph + (size_t)ks * BKT) : z;
    }
  };
  auto cvt4 = [](float4 f) {
    half4v h;
    h[0] = (_Float16)f.x; h[1] = (_Float16)f.y;
    h[2] = (_Float16)f.z; h[3] = (_Float16)f.w;
    return h;
  };
  auto stage_write = [&](int buf) {
    if constexpr (!AFP16) {
      *(half4v*)&Ah[buf][sb0] = cvt4(f0);
      *(half4v*)&Ah[buf][sb1] = cvt4(f1);
    } else if constexpr (BKT == 64) {
      *(half8*)&Ah[buf][sb0] = h8;
    } else {
      *(half4v*)&Ah[buf][sb0] = h4;
    }
  };

  aload(0);
  stage_write(0);
  __syncthreads();

  for (int ks = 0; ks < nK; ++ks) {
    const int cur = ks & 1;
    const int nxt = cur ^ 1;
    const bool have_next = (ks + 1 < nK);
    if (have_next) aload(ks + 1);

    #pragma unroll
    for (int kk = 0; kk < NKK; ++kk) {
      const int kbg = ks * NKK + kk;
      half8 ah = *(const half8*)&Ah[cur][(wr * NKK + kk) * 512 + lane * 8];
      const size_t bo0 = ((size_t)(cb0 * nKB + kbg) * 64 + lane) * 8;
      half8 bh0 = *(const half8*)(Bh + bo0);
      acc0 = __builtin_amdgcn_mfma_f32_32x32x16_f16(ah, bh0, acc0, 0, 0, 0);
      if constexpr (NCB == 2) {
        const size_t bo1 = ((size_t)((cb0 + 1) * nKB + kbg) * 64 + lane) * 8;
        half8 bh1 = *(const half8*)(Bh + bo1);
        acc1 = __builtin_amdgcn_mfma_f32_32x32x16_f16(ah, bh1, acc1, 0, 0, 0);
      }
    }

    if (have_next) stage_write(nxt);
    __syncthreads();
  }

  auto epi = [&](const f32x16& acc, int cb) {
    int cc = cb * 32 + (lane & 31);
    float bv;
    if constexpr (OUTMODE == 3) bv = (cc < 128) ? bias[cc] : bias2[cc - 128];
    else                        bv = (cc < M) ? bias[cc] : 0.f;
    #pragma unroll
    for (int r = 0; r < 16; ++r) {
      int rr = row0 + wr * 32 + (r & 3) + 8 * (r >> 2) + 4 * (lane >> 5);
      if (rr < N && cc < M) {
        float v = acc[r] + bv;
        if (ACT) v = v > 0.f ? v : (__expf(v) - 1.f);
        if constexpr (OUTMODE == 0)      C[(size_t)rr * M + cc] = v;
        else if constexpr (OUTMODE == 1) C16a[(size_t)rr * M + cc] = f2h(v);
        else {
          if (cc < 128) C16a[(size_t)rr * 128 + cc] = f2h(v);
          else          C16b[(size_t)rr * 128 + (cc - 128)] = f2h(v);
        }
      }
    }
  };
  epi(acc0, cb0);
  if constexpr (NCB == 2) epi(acc1, cb0 + 1);
}

// ---------------- CSR scans ---------------------------------------------------
__global__ __launch_bounds__(256) void k_scan1(const int* __restrict__ deg,
    int* __restrict__ rowstart, int* __restrict__ blocksum) {
  __shared__ int sm[256];
  int b = blockIdx.x, t = threadIdx.x;
  int i = b * 256 + t;
  int v = (i < NN) ? deg[i] : 0;
  sm[t] = v;
  __syncthreads();
  #pragma unroll
  for (int off = 1; off < 256; off <<= 1) {
    int u = (t >= off) ? sm[t - off] : 0;
    __syncthreads();
    sm[t] += u;
    __syncthreads();
  }
  if (i < NN) rowstart[i + 1] = sm[t];
  if (t == 255) blocksum[b] = sm[255];
}

__global__ __launch_bounds__(256) void k_scan2(int* __restrict__ blocksum, int nb) {
  __shared__ int sm[256];
  int t = threadIdx.x;
  int v = (t < nb) ? blocksum[t] : 0;
  sm[t] = v;
  __syncthreads();
  #pragma unroll
  for (int off = 1; off < 256; off <<= 1) {
    int u = (t >= off) ? sm[t - off] : 0;
    __syncthreads();
    sm[t] += u;
    __syncthreads();
  }
  if (t < nb) blocksum[t] = (t == 0) ? 0 : sm[t - 1];
}

__global__ __launch_bounds__(256) void k_scan3(int* __restrict__ rowstart,
    const int* __restrict__ blocksum) {
  int b = blockIdx.x, t = threadIdx.x;
  int i = b * 256 + t;
  if (i == 0) rowstart[0] = 0;
  if (i < NN) rowstart[i + 1] += blocksum[b];
}

// -------- fused GATv2 edge+node: masked 8-edge chunks, 2-deep pipeline --------
// While chunk j's softmax update computes, chunk j+8's srcp indices and row
// gathers are already issued into named registers (16 gathers in flight).
__global__ __launch_bounds__(256) void k_gat(const ushort_t* __restrict__ xl,
    const ushort_t* __restrict__ xr, const int* __restrict__ srcp,
    const int* __restrict__ rowstart, const float* __restrict__ att,
    const float* __restrict__ bias, ushort_t* __restrict__ out)
{
  const int g = threadIdx.x >> 5;
  const int c = threadIdx.x & 31;
  const int n = blockIdx.x * 8 + g;
  const int r0 = rowstart[n], r1 = rowstart[n + 1];
  half4v xrh = *(const half4v*)(xr + (size_t)n * 128 + 4 * c);
  const half2v xr01 = {xrh[0], xrh[1]};
  const half2v xr23 = {xrh[2], xrh[3]};
  const float4 atv = *(const float4*)(att + 4 * c);
  const half2v at01 = {(_Float16)atv.x, (_Float16)atv.y};
  const half2v at23 = {(_Float16)atv.z, (_Float16)atv.w};
  const half2v k02 = {(_Float16)0.2f, (_Float16)0.2f};

  float m = -1e30f, ssum = 0.f;
  float a0 = 0.f, a1 = 0.f, a2 = 0.f, a3 = 0.f;

  auto ldx = [&](int s) -> half4v {
    return *(const half4v*)(xl + (size_t)s * 128 + 4 * c);
  };
  // logit from a preloaded row
  auto lgv = [&](half4v hv, float4& xs) -> float {
    xs.x = (float)hv[0]; xs.y = (float)hv[1];
    xs.z = (float)hv[2]; xs.w = (float)hv[3];
    half2v u01 = half2v{hv[0], hv[1]} + xr01;
    half2v u23 = half2v{hv[2], hv[3]} + xr23;
    u01 = __builtin_elementwise_max(u01, u01 * k02);
    u23 = __builtin_elementwise_max(u23, u23 * k02);
    float l = fdot2(u01, at01, fdot2(u23, at23, 0.f));
    l += __shfl_xor(l, 1);
    l += __shfl_xor(l, 2);
    l += __shfl_xor(l, 4);
    return l;
  };

  const int je = r1 - 1;
  // prologue: load chunk 0
  half4v h0, h1, h2, h3, h4, h5, h6, h7;
  {
    int s0 = srcp[r0];
    int s1 = srcp[min(r0 + 1, je)], s2 = srcp[min(r0 + 2, je)];
    int s3 = srcp[min(r0 + 3, je)], s4 = srcp[min(r0 + 4, je)];
    int s5 = srcp[min(r0 + 5, je)], s6 = srcp[min(r0 + 6, je)];
    int s7 = srcp[min(r0 + 7, je)];
    h0 = ldx(s0); h1 = ldx(s1); h2 = ldx(s2); h3 = ldx(s3);
    h4 = ldx(s4); h5 = ldx(s5); h6 = ldx(s6); h7 = ldx(s7);
  }

  for (int j = r0; j < r1; j += 8) {
    const int jn = j + 8;
    const bool hn = jn < r1;
    // issue next chunk's gathers (independent of current update)
    half4v g0 = {}, g1 = {}, g2 = {}, g3 = {}, g4 = {}, g5 = {}, g6 = {}, g7 = {};
    if (hn) {
      int t0 = srcp[jn];
      int t1 = srcp[min(jn + 1, je)], t2 = srcp[min(jn + 2, je)];
      int t3 = srcp[min(jn + 3, je)], t4 = srcp[min(jn + 4, je)];
      int t5 = srcp[min(jn + 5, je)], t6 = srcp[min(jn + 6, je)];
      int t7 = srcp[min(jn + 7, je)];
      g0 = ldx(t0); g1 = ldx(t1); g2 = ldx(t2); g3 = ldx(t3);
      g4 = ldx(t4); g5 = ldx(t5); g6 = ldx(t6); g7 = ldx(t7);
    }

    float4 x0, x1, x2, x3, x4, x5, x6, x7;
    float l0 = lgv(h0, x0), l1 = lgv(h1, x1), l2 = lgv(h2, x2), l3 = lgv(h3, x3);
    float l4 = lgv(h4, x4), l5 = lgv(h5, x5), l6 = lgv(h6, x6), l7 = lgv(h7, x7);
    l1 = (j + 1 < r1) ? l1 : -1e30f;
    l2 = (j + 2 < r1) ? l2 : -1e30f;
    l3 = (j + 3 < r1) ? l3 : -1e30f;
    l4 = (j + 4 < r1) ? l4 : -1e30f;
    l5 = (j + 5 < r1) ? l5 : -1e30f;
    l6 = (j + 6 < r1) ? l6 : -1e30f;
    l7 = (j + 7 < r1) ? l7 : -1e30f;
    float mloc = fmaxf(fmaxf(fmaxf(l0, l1), fmaxf(l2, l3)),
                       fmaxf(fmaxf(l4, l5), fmaxf(l6, l7)));
    float mn = fmaxf(m, mloc);
    float sc = __expf(m - mn);
    float p0 = __expf(l0 - mn), p1 = __expf(l1 - mn);
    float p2 = __expf(l2 - mn), p3 = __expf(l3 - mn);
    float p4 = __expf(l4 - mn), p5 = __expf(l5 - mn);
    float p6 = __expf(l6 - mn), p7 = __expf(l7 - mn);
    ssum = ssum * sc + (((p0 + p1) + (p2 + p3)) + ((p4 + p5) + (p6 + p7)));
    a0 = a0 * sc + (((p0 * x0.x + p1 * x1.x) + (p2 * x2.x + p3 * x3.x)) +
                    ((p4 * x4.x + p5 * x5.x) + (p6 * x6.x + p7 * x7.x)));
    a1 = a1 * sc + (((p0 * x0.y + p1 * x1.y) + (p2 * x2.y + p3 * x3.y)) +
                    ((p4 * x4.y + p5 * x5.y) + (p6 * x6.y + p7 * x7.y)));
    a2 = a2 * sc + (((p0 * x0.z + p1 * x1.z) + (p2 * x2.z + p3 * x3.z)) +
                    ((p4 * x4.z + p5 * x5.z) + (p6 * x6.z + p7 * x7.z)));
    a3 = a3 * sc + (((p0 * x0.w + p1 * x1.w) + (p2 * x2.w + p3 * x3.w)) +
                    ((p4 * x4.w + p5 * x5.w) + (p6 * x6.w + p7 * x7.w)));
    m = mn;

    h0 = g0; h1 = g1; h2 = g2; h3 = g3;
    h4 = g4; h5 = g5; h6 = g6; h7 = g7;
  }

  const float4 bv = *(const float4*)(bias + 4 * c);
  float rinv = 1.f / (ssum + 1e-16f);
  float o0 = a0 * rinv + bv.x;
  float o1 = a1 * rinv + bv.y;
  float o2 = a2 * rinv + bv.z;
  float o3 = a3 * rinv + bv.w;
  o0 = o0 > 0.f ? o0 : (__expf(o0) - 1.f);
  o1 = o1 > 0.f ? o1 : (__expf(o1) - 1.f);
  o2 = o2 > 0.f ? o2 : (__expf(o2) - 1.f);
  o3 = o3 > 0.f ? o3 : (__expf(o3) - 1.f);
  half4v ov;
  ov[0] = (_Float16)o0; ov[1] = (_Float16)o1;
  ov[2] = (_Float16)o2; ov[3] = (_Float16)o3;
  *(half4v*)(out + (size_t)n * 128 + 4 * c) = ov;
}

__global__ void k_report_ws(float* out, int out_size, float wsz) {
  int i = blockIdx.x * 256 + threadIdx.x;
  if (i < out_size) out[i] = (i == 0) ? wsz : 0.f;
}

// -----------------------------------------------------------------------------
extern "C" void kernel_launch(void* const* d_in, const int* in_sizes, int n_in,
                              void* d_out, int out_size, void* d_ws, size_t ws_size,
                              hipStream_t stream)
{
  const float* x    = (const float*)d_in[0];
  const int*   ei   = (const int*)d_in[1];     // int32 [2,E] row-major
  const float* Wp   = (const float*)d_in[2];  const float* bp    = (const float*)d_in[3];
  const float* Wl1  = (const float*)d_in[4];  const float* bl1   = (const float*)d_in[5];
  const float* Wr1  = (const float*)d_in[6];  const float* br1   = (const float*)d_in[7];
  const float* att1 = (const float*)d_in[8];  const float* bias1 = (const float*)d_in[9];
  const float* Wl2  = (const float*)d_in[10]; const float* bl2   = (const float*)d_in[11];
  const float* Wr2  = (const float*)d_in[12]; const float* br2   = (const float*)d_in[13];
  const float* att2 = (const float*)d_in[14]; const float* bias2 = (const float*)d_in[15];
  const float* W1   = (const float*)d_in[16]; const float* b1    = (const float*)d_in[17];
  const float* W2   = (const float*)d_in[18]; const float* b2    = (const float*)d_in[19];
  float* out = (float*)d_out;

  constexpr size_t NEED = 122300000;
  if (ws_size < NEED) {
    k_report_ws<<<(out_size + 255) / 256, 256, 0, stream>>>(out, out_size, (float)ws_size);
    return;
  }
  char* ws = (char*)d_ws;
  ushort_t* h1h   = (ushort_t*)(ws + 0);          // 50000*128 fp16
  ushort_t* h2h   = (ushort_t*)(ws + 25600000);
  ushort_t* xlh   = (ushort_t*)(ws + 51200000);
  ushort_t* xrh   = (ushort_t*)(ws + 76800000);
  ushort_t* wb    = (ushort_t*)(ws + 108800000);
  int*      srcp  = (int*)(ws + 115200000);
  int*      rank  = (int*)(ws + 118400000);
  int*      deg   = (int*)(ws + 121600000);
  int*      rowst = (int*)(ws + 122000000);
  int*      bsum  = (int*)(ws + 122250000);

  ushort_t* Wph  = wb;             // 131072
  ushort_t* WB1h = wb + 131072;    // 65536
  ushort_t* WB2h = wb + 196608;    // 32768
  ushort_t* W1h  = wb + 229376;    // 4096
  ushort_t* W2h  = wb + 233472;    // 1024

  hipMemsetAsync(deg, 0, NN * sizeof(int), stream);

  // FAT A: weight pre-transform + degrank in one launch
  k_preA<<<WCONV_BLOCKS + DEGRANK_BLOCKS, 256, 0, stream>>>(
      Wp, Wl1, Wr1, Wl2, Wr2, W1, W2, wb, ei, deg, rank);

  constexpr int NB = (NN + 255) / 256;
  k_scan1<<<NB, 256, 0, stream>>>(deg, rowst, bsum);
  k_scan2<<<1, 256, 0, stream>>>(bsum, NB);
  k_scan3<<<NB, 256, 0, stream>>>(rowst, bsum);

  // FAT B: mega1 (proj+L1) + scatter in one launch
  k_mainB<<<GX + SCAT_BLOCKS, 512, 0, stream>>>(
      x, Wph, WB1h, bp, bl1, br1, xlh, xrh, NN, ei, rowst, rank, srcp);
  k_gat<<<NN/8, 256, 0, stream>>>(xlh, xrh, srcp, rowst, att1, bias1, h1h);

  // GAT layer 2: fused, M=256, K=128, single pass
  gemm_mfma<0,3,64,1,2><<<dim3(GX, 1), 512, 0, stream>>>(
      h1h, WB2h, bl2, br2, nullptr, xlh, xrh, NN, 256, 128);
  k_gat<<<NN/8, 256, 0, stream>>>(xlh, xrh, srcp, rowst, att2, bias2, h2h);

  // MEGAKERNEL 2: MLP1 + MLP2 -> out
  gemm_mlp<<<GX, 512, 0, stream>>>(h2h, W1h, W2h, b1, b2, out, NN);
}

// Round 26
// 219.220 us; speedup vs baseline: 1.0601x; 1.0601x over previous
//
#include <hip/hip_runtime.h>
#include <cstdint>
#include <cstddef>

constexpr int NN = 50000;
constexpr int NE = 800000;

typedef _Float16 half8 __attribute__((ext_vector_type(8)));
typedef _Float16 half4v __attribute__((ext_vector_type(4)));
typedef _Float16 half2v __attribute__((ext_vector_type(2)));
typedef float f32x16 __attribute__((ext_vector_type(16)));
typedef unsigned short ushort_t;

__device__ inline ushort_t f2h(float f) {
  _Float16 h = (_Float16)f;
  return __builtin_bit_cast(ushort_t, h);
}

#if __has_builtin(__builtin_amdgcn_fdot2)
__device__ inline float fdot2(half2v a, half2v b, float c) {
  return __builtin_amdgcn_fdot2(a, b, c, false);
}
#else
__device__ inline float fdot2(half2v a, half2v b, float c) {
  return c + (float)a[0] * (float)b[0] + (float)a[1] * (float)b[1];
}
#endif

// ---- FAT KERNEL A: weight pre-transform (blocks 0..915) + degrank (rest) -----
constexpr int WCONV_BLOCKS = (234496 + 255) / 256;          // 916
constexpr int DEGRANK_BLOCKS = (NE + 255) / 256;            // 3125
__global__ __launch_bounds__(256) void k_preA(const float* __restrict__ Wp,
    const float* __restrict__ Wl1, const float* __restrict__ Wr1,
    const float* __restrict__ Wl2, const float* __restrict__ Wr2,
    const float* __restrict__ W1, const float* __restrict__ W2,
    ushort_t* __restrict__ wb, const int* __restrict__ ei,
    int* __restrict__ deg, int* __restrict__ rank)
{
  if (blockIdx.x < WCONV_BLOCKS) {
    int idx = blockIdx.x * 256 + threadIdx.x;
    if (idx >= 234496) return;
    const float* W;
    int M, K, base, li;
    if (idx < 131072)      { W = Wp;  M = 256; K = 512; base = 0;      li = idx; }
    else if (idx < 163840) { W = Wl1; M = 128; K = 256; base = 131072; li = idx - 131072; }
    else if (idx < 196608) { W = Wr1; M = 128; K = 256; base = 163840; li = idx - 163840; }
    else if (idx < 212992) { W = Wl2; M = 128; K = 128; base = 196608; li = idx - 196608; }
    else if (idx < 229376) { W = Wr2; M = 128; K = 128; base = 212992; li = idx - 212992; }
    else if (idx < 233472) { W = W1;  M = 32;  K = 128; base = 229376; li = idx - 229376; }
    else                   { W = W2;  M = 10;  K = 32;  base = 233472; li = idx - 233472; }
    int j = li & 7;
    int l = (li >> 3) & 63;
    int blk = li >> 9;
    int nKB = K >> 4;
    int cb = blk / nKB, kb = blk - cb * nKB;
    int col = cb * 32 + (l & 31);
    int k = kb * 16 + ((l >> 5) & 1) * 8 + j;
    float v = (col < M) ? W[(size_t)col * K + k] : 0.f;
    wb[base + li] = f2h(v);
  } else {
    int e = (blockIdx.x - WCONV_BLOCKS) * 256 + threadIdx.x;
    if (e >= NE) return;
    int d = ei[NE + e];
    rank[e] = atomicAdd(&deg[d], 1);
  }
}

// ---- FAT KERNEL B: mega1 (proj+L1 GEMM, blocks 0..GX-1) + scatter (rest) -----
constexpr int GX = (NN + 63) / 64;                          // 782
constexpr int SCAT_BLOCKS = (NE + 511) / 512;               // 1563
__global__ __launch_bounds__(512) void k_mainB(const float* __restrict__ x,
    const ushort_t* __restrict__ WpF, const ushort_t* __restrict__ WB1,
    const float* __restrict__ bp, const float* __restrict__ bl1,
    const float* __restrict__ br1, ushort_t* __restrict__ xlh,
    ushort_t* __restrict__ xrh, int N,
    const int* __restrict__ ei, const int* __restrict__ rowst,
    const int* __restrict__ rank, int* __restrict__ srcp)
{
  constexpr int NKK = 4;            // BKT=64
  constexpr int nKB1 = 32;          // K1=512
  constexpr int nK1 = 8;
  __shared__ ushort_t Ah[2][2 * NKK * 512];
  __shared__ ushort_t H0[16384];

  if (blockIdx.x >= GX) {
    int e = (blockIdx.x - GX) * 512 + threadIdx.x;
    if (e < NE) {
      int d = ei[NE + e];
      srcp[rowst[d] + rank[e]] = ei[e];
    }
    return;
  }

  const int t = threadIdx.x;
  const int lane = t & 63;
  const int wid = t >> 6;
  const int wr = wid >> 2;
  const int wc = wid & 3;
  const int row0 = blockIdx.x * 64;
  const int cb0 = wc * 2;

  const int s_r = t >> 4, s_k = (t & 15) * 4;
  const int sb0 = (s_k >> 4) * 512 + (s_r + 32 * ((s_k >> 3) & 1)) * 8 + (s_k & 7);
  const int sb1 = sb0 + NKK * 512;
  const bool ok0 = (row0 + s_r) < N;
  const bool ok1 = (row0 + s_r + 32) < N;
  const float* ap0 = x + (size_t)(row0 + s_r) * 512 + s_k;
  const float* ap1 = x + (size_t)(row0 + s_r + 32) * 512 + s_k;

  f32x16 acc0 = {}, acc1 = {};
  float4 f0 = make_float4(0, 0, 0, 0), f1 = make_float4(0, 0, 0, 0);

  auto aload = [&](int ks) {
    f0 = make_float4(0, 0, 0, 0);
    f1 = make_float4(0, 0, 0, 0);
    if (ok0) f0 = *(const float4*)(ap0 + (size_t)ks * 64);
    if (ok1) f1 = *(const float4*)(ap1 + (size_t)ks * 64);
  };
  auto cvt4 = [](float4 f) {
    half4v h;
    h[0] = (_Float16)f.x; h[1] = (_Float16)f.y;
    h[2] = (_Float16)f.z; h[3] = (_Float16)f.w;
    return h;
  };
  auto stage_write = [&](int buf) {
    *(half4v*)&Ah[buf][sb0] = cvt4(f0);
    *(half4v*)&Ah[buf][sb1] = cvt4(f1);
  };

  aload(0);
  stage_write(0);
  __syncthreads();

  for (int ks = 0; ks < nK1; ++ks) {
    const int cur = ks & 1;
    const int nxt = cur ^ 1;
    const bool have_next = (ks + 1 < nK1);
    if (have_next) aload(ks + 1);

    #pragma unroll
    for (int kk = 0; kk < NKK; ++kk) {
      const int kbg = ks * NKK + kk;
      half8 ah = *(const half8*)&Ah[cur][(wr * NKK + kk) * 512 + lane * 8];
      const size_t bo0 = ((size_t)(cb0 * nKB1 + kbg) * 64 + lane) * 8;
      half8 bh0 = *(const half8*)(WpF + bo0);
      acc0 = __builtin_amdgcn_mfma_f32_32x32x16_f16(ah, bh0, acc0, 0, 0, 0);
      const size_t bo1 = ((size_t)((cb0 + 1) * nKB1 + kbg) * 64 + lane) * 8;
      half8 bh1 = *(const half8*)(WpF + bo1);
      acc1 = __builtin_amdgcn_mfma_f32_32x32x16_f16(ah, bh1, acc1, 0, 0, 0);
    }

    if (have_next) stage_write(nxt);
    __syncthreads();
  }

  {
    int col = cb0 * 32 + (lane & 31);
    float bv = bp[col];
    #pragma unroll
    for (int r = 0; r < 16; ++r) {
      int row = wr * 32 + (r & 3) + 8 * (r >> 2) + 4 * (lane >> 5);
      float v = acc0[r] + bv;
      v = v > 0.f ? v : (__expf(v) - 1.f);
      H0[((row >> 5) * 16 + (col >> 4)) * 512 +
         ((row & 31) + 32 * ((col >> 3) & 1)) * 8 + (col & 7)] = f2h(v);
    }
    int col1 = col + 32;
    float bv1 = bp[col1];
    #pragma unroll
    for (int r = 0; r < 16; ++r) {
      int row = wr * 32 + (r & 3) + 8 * (r >> 2) + 4 * (lane >> 5);
      float v = acc1[r] + bv1;
      v = v > 0.f ? v : (__expf(v) - 1.f);
      H0[((row >> 5) * 16 + (col1 >> 4)) * 512 +
         ((row & 31) + 32 * ((col1 >> 3) & 1)) * 8 + (col1 & 7)] = f2h(v);
    }
  }
  __syncthreads();

  f32x16 acc2a = {}, acc2b = {};
  #pragma unroll
  for (int kk = 0; kk < 16; ++kk) {
    half8 ah = *(const half8*)&H0[(wr * 16 + kk) * 512 + lane * 8];
    const size_t bo0 = ((size_t)(cb0 * 16 + kk) * 64 + lane) * 8;
    half8 bh0 = *(const half8*)(WB1 + bo0);
    acc2a = __builtin_amdgcn_mfma_f32_32x32x16_f16(ah, bh0, acc2a, 0, 0, 0);
    const size_t bo1 = ((size_t)((cb0 + 1) * 16 + kk) * 64 + lane) * 8;
    half8 bh1 = *(const half8*)(WB1 + bo1);
    acc2b = __builtin_amdgcn_mfma_f32_32x32x16_f16(ah, bh1, acc2b, 0, 0, 0);
  }

  auto epi2 = [&](const f32x16& acc, int cb) {
    int cc = cb * 32 + (lane & 31);
    float bv = (cc < 128) ? bl1[cc] : br1[cc - 128];
    #pragma unroll
    for (int r = 0; r < 16; ++r) {
      int rr = row0 + wr * 32 + (r & 3) + 8 * (r >> 2) + 4 * (lane >> 5);
      if (rr < N) {
        float v = acc[r] + bv;
        if (cc < 128) xlh[(size_t)rr * 128 + cc] = f2h(v);
        else          xrh[(size_t)rr * 128 + (cc - 128)] = f2h(v);
      }
    }
  };
  epi2(acc2a, cb0);
  epi2(acc2b, cb0 + 1);
}

// ---- MEGAKERNEL 2: MLP1 (K=128 -> h3 tile in LDS) + MLP2 (K=32 -> out) -------
__global__ __launch_bounds__(512) void gemm_mlp(const ushort_t* __restrict__ h2,
    const ushort_t* __restrict__ W1F, const ushort_t* __restrict__ W2F,
    const float* __restrict__ b1, const float* __restrict__ b2,
    float* __restrict__ out, int N)
{
  constexpr int NKK = 4;
  __shared__ ushort_t Ah[2][2 * NKK * 512];
  __shared__ ushort_t H3[2048];
  const int t = threadIdx.x;
  const int lane = t & 63;
  const int wid = t >> 6;
  const int wr = wid >> 2;
  const int wc = wid & 3;
  const int row0 = blockIdx.x * 64;

  const int s_r = t >> 3, s_k = (t & 7) * 8;
  const int sb0 = ((s_r >> 5) * NKK + (s_k >> 4)) * 512 +
                  ((s_r & 31) + 32 * ((s_k >> 3) & 1)) * 8;
  const bool ok0 = (row0 + s_r) < N;
  const ushort_t* aph = h2 + (size_t)(row0 + s_r) * 128 + s_k;

  f32x16 acc = {};
  half8 h8 = {};

  auto aload = [&](int ks) {
    half8 z = {};
    h8 = ok0 ? *(const half8*)(aph + (size_t)ks * 64) : z;
  };

  aload(0);
  *(half8*)&Ah[0][sb0] = h8;
  __syncthreads();

  for (int ks = 0; ks < 2; ++ks) {
    const int cur = ks & 1;
    const bool have_next = (ks == 0);
    if (have_next) aload(1);

    if (wc == 0) {
      #pragma unroll
      for (int kk = 0; kk < NKK; ++kk) {
        const int kbg = ks * NKK + kk;
        half8 ah = *(const half8*)&Ah[cur][(wr * NKK + kk) * 512 + lane * 8];
        half8 bh = *(const half8*)(W1F + ((size_t)kbg * 64 + lane) * 8);
        acc = __builtin_amdgcn_mfma_f32_32x32x16_f16(ah, bh, acc, 0, 0, 0);
      }
    }

    if (have_next) *(half8*)&Ah[cur ^ 1][sb0] = h8;
    __syncthreads();
  }

  if (wc == 0) {
    int cc = lane & 31;
    float bv = b1[cc];
    #pragma unroll
    for (int r = 0; r < 16; ++r) {
      int row = wr * 32 + (r & 3) + 8 * (r >> 2) + 4 * (lane >> 5);
      float v = acc[r] + bv;
      v = v > 0.f ? v : (__expf(v) - 1.f);
      H3[((row >> 5) * 2 + (cc >> 4)) * 512 +
         ((row & 31) + 32 * ((cc >> 3) & 1)) * 8 + (cc & 7)] = f2h(v);
    }
  }
  __syncthreads();

  if (wc == 0) {
    f32x16 acc2 = {};
    #pragma unroll
    for (int kk = 0; kk < 2; ++kk) {
      half8 ah = *(const half8*)&H3[(wr * 2 + kk) * 512 + lane * 8];
      half8 bh = *(const half8*)(W2F + ((size_t)kk * 64 + lane) * 8);
      acc2 = __builtin_amdgcn_mfma_f32_32x32x16_f16(ah, bh, acc2, 0, 0, 0);
    }
    int cc = lane & 31;
    if (cc < 10) {
      float bv = b2[cc];
      #pragma unroll
      for (int r = 0; r < 16; ++r) {
        int rr = row0 + wr * 32 + (r & 3) + 8 * (r >> 2) + 4 * (lane >> 5);
        if (rr < N) out[(size_t)rr * 10 + cc] = acc2[r] + bv;
      }
    }
  }
}

// ---- fp16 MFMA GEMM (r17 body) for the L2 fused layer ------------------------
template<int ACT, int OUTMODE, int BKT, int AFP16, int NCB>
__global__ __launch_bounds__(512) void gemm_mfma(const void* __restrict__ Av,
    const ushort_t* __restrict__ Bh,
    const float* __restrict__ bias, const float* __restrict__ bias2,
    float* __restrict__ C, ushort_t* __restrict__ C16a,
    ushort_t* __restrict__ C16b, int N, int M, int K)
{
  constexpr int NKK = BKT / 16;
  __shared__ ushort_t Ah[2][2 * NKK * 512];
  const int t = threadIdx.x;
  const int lane = t & 63;
  const int wid = t >> 6;
  const int wr = wid >> 2;
  const int wc = wid & 3;
  const int row0 = blockIdx.x * 64;
  const int col0 = blockIdx.y * (128 * NCB);
  const int nKB = K >> 4;
  const int nK = K / BKT;
  const int cb0 = (col0 >> 5) + wc * NCB;

  int s_r, s_k, sb0, sb1 = 0;
  bool ok0 = false, ok1 = false;
  if constexpr (!AFP16) {
    s_r = t >> 4; s_k = (t & 15) * 4;
    sb0 = (s_k >> 4) * 512 + (s_r + 32 * ((s_k >> 3) & 1)) * 8 + (s_k & 7);
    sb1 = sb0 + NKK * 512;
    ok0 = (row0 + s_r) < N;
    ok1 = (row0 + s_r + 32) < N;
  } else if constexpr (BKT == 64) {
    s_r = t >> 3; s_k = (t & 7) * 8;
    sb0 = ((s_r >> 5) * NKK + (s_k >> 4)) * 512 +
          ((s_r & 31) + 32 * ((s_k >> 3) & 1)) * 8;
    ok0 = (row0 + s_r) < N;
  } else {
    s_r = t >> 3; s_k = (t & 7) * 4;
    sb0 = ((s_r >> 5) * NKK + (s_k >> 4)) * 512 +
          ((s_r & 31) + 32 * ((s_k >> 3) & 1)) * 8 + (s_k & 7);
    ok0 = (row0 + s_r) < N;
  }
  const float*    ap0 = (const float*)Av + (size_t)(row0 + s_r) * K + s_k;
  const float*    ap1 = (const float*)Av + (size_t)(row0 + s_r + 32) * K + s_k;
  const ushort_t* aph = (const ushort_t*)Av + (size_t)(row0 + s_r) * K + s_k;

  f32x16 acc0 = {}, acc1 = {};
  float4 f0 = make_float4(0, 0, 0, 0), f1 = make_float4(0, 0, 0, 0);
  half8 h8 = {};
  half4v h4 = {};

  auto aload = [&](int ks) {
    if constexpr (!AFP16) {
      f0 = make_float4(0, 0, 0, 0);
      f1 = make_float4(0, 0, 0, 0);
      if (ok0) f0 = *(const float4*)(ap0 + (size_t)ks * BKT);
      if (ok1) f1 = *(const float4*)(ap1 + (size_t)ks * BKT);
    } else if constexpr (BKT == 64) {
      half8 z = {};
      h8 = ok0 ? *(const half8*)(aph + (size_t)ks * BKT) : z;
    } else {
      half4v z = {};
      h4 = ok0 ? *(const half4v*)(aph + (size_t)ks * BKT) : z;
    }
  };
  auto cvt4 = [](float4 f) {
    half4v h;
    h[0] = (_Float16)f.x; h[1] = (_Float16)f.y;
    h[2] = (_Float16)f.z; h[3] = (_Float16)f.w;
    return h;
  };
  auto stage_write = [&](int buf) {
    if constexpr (!AFP16) {
      *(half4v*)&Ah[buf][sb0] = cvt4(f0);
      *(half4v*)&Ah[buf][sb1] = cvt4(f1);
    } else if constexpr (BKT == 64) {
      *(half8*)&Ah[buf][sb0] = h8;
    } else {
      *(half4v*)&Ah[buf][sb0] = h4;
    }
  };

  aload(0);
  stage_write(0);
  __syncthreads();

  for (int ks = 0; ks < nK; ++ks) {
    const int cur = ks & 1;
    const int nxt = cur ^ 1;
    const bool have_next = (ks + 1 < nK);
    if (have_next) aload(ks + 1);

    #pragma unroll
    for (int kk = 0; kk < NKK; ++kk) {
      const int kbg = ks * NKK + kk;
      half8 ah = *(const half8*)&Ah[cur][(wr * NKK + kk) * 512 + lane * 8];
      const size_t bo0 = ((size_t)(cb0 * nKB + kbg) * 64 + lane) * 8;
      half8 bh0 = *(const half8*)(Bh + bo0);
      acc0 = __builtin_amdgcn_mfma_f32_32x32x16_f16(ah, bh0, acc0, 0, 0, 0);
      if constexpr (NCB == 2) {
        const size_t bo1 = ((size_t)((cb0 + 1) * nKB + kbg) * 64 + lane) * 8;
        half8 bh1 = *(const half8*)(Bh + bo1);
        acc1 = __builtin_amdgcn_mfma_f32_32x32x16_f16(ah, bh1, acc1, 0, 0, 0);
      }
    }

    if (have_next) stage_write(nxt);
    __syncthreads();
  }

  auto epi = [&](const f32x16& acc, int cb) {
    int cc = cb * 32 + (lane & 31);
    float bv;
    if constexpr (OUTMODE == 3) bv = (cc < 128) ? bias[cc] : bias2[cc - 128];
    else                        bv = (cc < M) ? bias[cc] : 0.f;
    #pragma unroll
    for (int r = 0; r < 16; ++r) {
      int rr = row0 + wr * 32 + (r & 3) + 8 * (r >> 2) + 4 * (lane >> 5);
      if (rr < N && cc < M) {
        float v = acc[r] + bv;
        if (ACT) v = v > 0.f ? v : (__expf(v) - 1.f);
        if constexpr (OUTMODE == 0)      C[(size_t)rr * M + cc] = v;
        else if constexpr (OUTMODE == 1) C16a[(size_t)rr * M + cc] = f2h(v);
        else {
          if (cc < 128) C16a[(size_t)rr * 128 + cc] = f2h(v);
          else          C16b[(size_t)rr * 128 + (cc - 128)] = f2h(v);
        }
      }
    }
  };
  epi(acc0, cb0);
  if constexpr (NCB == 2) epi(acc1, cb0 + 1);
}

// ---------------- CSR scans ---------------------------------------------------
__global__ __launch_bounds__(256) void k_scan1(const int* __restrict__ deg,
    int* __restrict__ rowstart, int* __restrict__ blocksum) {
  __shared__ int sm[256];
  int b = blockIdx.x, t = threadIdx.x;
  int i = b * 256 + t;
  int v = (i < NN) ? deg[i] : 0;
  sm[t] = v;
  __syncthreads();
  #pragma unroll
  for (int off = 1; off < 256; off <<= 1) {
    int u = (t >= off) ? sm[t - off] : 0;
    __syncthreads();
    sm[t] += u;
    __syncthreads();
  }
  if (i < NN) rowstart[i + 1] = sm[t];
  if (t == 255) blocksum[b] = sm[255];
}

__global__ __launch_bounds__(256) void k_scan2(int* __restrict__ blocksum, int nb) {
  __shared__ int sm[256];
  int t = threadIdx.x;
  int v = (t < nb) ? blocksum[t] : 0;
  sm[t] = v;
  __syncthreads();
  #pragma unroll
  for (int off = 1; off < 256; off <<= 1) {
    int u = (t >= off) ? sm[t - off] : 0;
    __syncthreads();
    sm[t] += u;
    __syncthreads();
  }
  if (t < nb) blocksum[t] = (t == 0) ? 0 : sm[t - 1];
}

__global__ __launch_bounds__(256) void k_scan3(int* __restrict__ rowstart,
    const int* __restrict__ blocksum) {
  int b = blockIdx.x, t = threadIdx.x;
  int i = b * 256 + t;
  if (i == 0) rowstart[0] = 0;
  if (i < NN) rowstart[i + 1] += blocksum[b];
}

// -------- fused GATv2 edge+node: masked full-width 8-edge chunks --------------
__global__ __launch_bounds__(256) void k_gat(const ushort_t* __restrict__ xl,
    const ushort_t* __restrict__ xr, const int* __restrict__ srcp,
    const int* __restrict__ rowstart, const float* __restrict__ att,
    const float* __restrict__ bias, ushort_t* __restrict__ out)
{
  const int g = threadIdx.x >> 5;
  const int c = threadIdx.x & 31;
  const int n = blockIdx.x * 8 + g;
  const int r0 = rowstart[n], r1 = rowstart[n + 1];
  half4v xrh = *(const half4v*)(xr + (size_t)n * 128 + 4 * c);
  const half2v xr01 = {xrh[0], xrh[1]};
  const half2v xr23 = {xrh[2], xrh[3]};
  const float4 atv = *(const float4*)(att + 4 * c);
  const half2v at01 = {(_Float16)atv.x, (_Float16)atv.y};
  const half2v at23 = {(_Float16)atv.z, (_Float16)atv.w};
  const half2v k02 = {(_Float16)0.2f, (_Float16)0.2f};

  float m = -1e30f, ssum = 0.f;
  float a0 = 0.f, a1 = 0.f, a2 = 0.f, a3 = 0.f;

  auto lg = [&](int s, float4& xs) -> float {
    half4v hv = *(const half4v*)(xl + (size_t)s * 128 + 4 * c);
    xs.x = (float)hv[0]; xs.y = (float)hv[1];
    xs.z = (float)hv[2]; xs.w = (float)hv[3];
    half2v u01 = half2v{hv[0], hv[1]} + xr01;
    half2v u23 = half2v{hv[2], hv[3]} + xr23;
    u01 = __builtin_elementwise_max(u01, u01 * k02);
    u23 = __builtin_elementwise_max(u23, u23 * k02);
    float l = fdot2(u01, at01, fdot2(u23, at23, 0.f));
    l += __shfl_xor(l, 1);
    l += __shfl_xor(l, 2);
    l += __shfl_xor(l, 4);
    return l;
  };

  const int je = r1 - 1;
  for (int j = r0; j < r1; j += 8) {
    int s0 = srcp[j];
    int s1 = srcp[min(j + 1, je)], s2 = srcp[min(j + 2, je)];
    int s3 = srcp[min(j + 3, je)], s4 = srcp[min(j + 4, je)];
    int s5 = srcp[min(j + 5, je)], s6 = srcp[min(j + 6, je)];
    int s7 = srcp[min(j + 7, je)];
    float4 x0, x1, x2, x3, x4, x5, x6, x7;
    float l0 = lg(s0, x0), l1 = lg(s1, x1), l2 = lg(s2, x2), l3 = lg(s3, x3);
    float l4 = lg(s4, x4), l5 = lg(s5, x5), l6 = lg(s6, x6), l7 = lg(s7, x7);
    l1 = (j + 1 < r1) ? l1 : -1e30f;
    l2 = (j + 2 < r1) ? l2 : -1e30f;
    l3 = (j + 3 < r1) ? l3 : -1e30f;
    l4 = (j + 4 < r1) ? l4 : -1e30f;
    l5 = (j + 5 < r1) ? l5 : -1e30f;
    l6 = (j + 6 < r1) ? l6 : -1e30f;
    l7 = (j + 7 < r1) ? l7 : -1e30f;
    float mloc = fmaxf(fmaxf(fmaxf(l0, l1), fmaxf(l2, l3)),
                       fmaxf(fmaxf(l4, l5), fmaxf(l6, l7)));
    float mn = fmaxf(m, mloc);
    float sc = __expf(m - mn);
    float p0 = __expf(l0 - mn), p1 = __expf(l1 - mn);
    float p2 = __expf(l2 - mn), p3 = __expf(l3 - mn);
    float p4 = __expf(l4 - mn), p5 = __expf(l5 - mn);
    float p6 = __expf(l6 - mn), p7 = __expf(l7 - mn);
    ssum = ssum * sc + (((p0 + p1) + (p2 + p3)) + ((p4 + p5) + (p6 + p7)));
    a0 = a0 * sc + (((p0 * x0.x + p1 * x1.x) + (p2 * x2.x + p3 * x3.x)) +
                    ((p4 * x4.x + p5 * x5.x) + (p6 * x6.x + p7 * x7.x)));
    a1 = a1 * sc + (((p0 * x0.y + p1 * x1.y) + (p2 * x2.y + p3 * x3.y)) +
                    ((p4 * x4.y + p5 * x5.y) + (p6 * x6.y + p7 * x7.y)));
    a2 = a2 * sc + (((p0 * x0.z + p1 * x1.z) + (p2 * x2.z + p3 * x3.z)) +
                    ((p4 * x4.z + p5 * x5.z) + (p6 * x6.z + p7 * x7.z)));
    a3 = a3 * sc + (((p0 * x0.w + p1 * x1.w) + (p2 * x2.w + p3 * x3.w)) +
                    ((p4 * x4.w + p5 * x5.w) + (p6 * x6.w + p7 * x7.w)));
    m = mn;
  }

  const float4 bv = *(const float4*)(bias + 4 * c);
  float rinv = 1.f / (ssum + 1e-16f);
  float o0 = a0 * rinv + bv.x;
  float o1 = a1 * rinv + bv.y;
  float o2 = a2 * rinv + bv.z;
  float o3 = a3 * rinv + bv.w;
  o0 = o0 > 0.f ? o0 : (__expf(o0) - 1.f);
  o1 = o1 > 0.f ? o1 : (__expf(o1) - 1.f);
  o2 = o2 > 0.f ? o2 : (__expf(o2) - 1.f);
  o3 = o3 > 0.f ? o3 : (__expf(o3) - 1.f);
  half4v ov;
  ov[0] = (_Float16)o0; ov[1] = (_Float16)o1;
  ov[2] = (_Float16)o2; ov[3] = (_Float16)o3;
  *(half4v*)(out + (size_t)n * 128 + 4 * c) = ov;
}

__global__ void k_report_ws(float* out, int out_size, float wsz) {
  int i = blockIdx.x * 256 + threadIdx.x;
  if (i < out_size) out[i] = (i == 0) ? wsz : 0.f;
}

// -----------------------------------------------------------------------------
extern "C" void kernel_launch(void* const* d_in, const int* in_sizes, int n_in,
                              void* d_out, int out_size, void* d_ws, size_t ws_size,
                              hipStream_t stream)
{
  const float* x    = (const float*)d_in[0];
  const int*   ei   = (const int*)d_in[1];     // int32 [2,E] row-major
  const float* Wp   = (const float*)d_in[2];  const float* bp    = (const float*)d_in[3];
  const float* Wl1  = (const float*)d_in[4];  const float* bl1   = (const float*)d_in[5];
  const float* Wr1  = (const float*)d_in[6];  const float* br1   = (const float*)d_in[7];
  const float* att1 = (const float*)d_in[8];  const float* bias1 = (const float*)d_in[9];
  const float* Wl2  = (const float*)d_in[10]; const float* bl2   = (const float*)d_in[11];
  const float* Wr2  = (const float*)d_in[12]; const float* br2   = (const float*)d_in[13];
  const float* att2 = (const float*)d_in[14]; const float* bias2 = (const float*)d_in[15];
  const float* W1   = (const float*)d_in[16]; const float* b1    = (const float*)d_in[17];
  const float* W2   = (const float*)d_in[18]; const float* b2    = (const float*)d_in[19];
  float* out = (float*)d_out;

  constexpr size_t NEED = 122300000;
  if (ws_size < NEED) {
    k_report_ws<<<(out_size + 255) / 256, 256, 0, stream>>>(out, out_size, (float)ws_size);
    return;
  }
  char* ws = (char*)d_ws;
  ushort_t* h1h   = (ushort_t*)(ws + 0);          // 50000*128 fp16
  ushort_t* h2h   = (ushort_t*)(ws + 25600000);
  ushort_t* xlh   = (ushort_t*)(ws + 51200000);
  ushort_t* xrh   = (ushort_t*)(ws + 76800000);
  ushort_t* wb    = (ushort_t*)(ws + 108800000);
  int*      srcp  = (int*)(ws + 115200000);
  int*      rank  = (int*)(ws + 118400000);
  int*      deg   = (int*)(ws + 121600000);
  int*      rowst = (int*)(ws + 122000000);
  int*      bsum  = (int*)(ws + 122250000);

  ushort_t* Wph  = wb;             // 131072
  ushort_t* WB1h = wb + 131072;    // 65536
  ushort_t* WB2h = wb + 196608;    // 32768
  ushort_t* W1h  = wb + 229376;    // 4096
  ushort_t* W2h  = wb + 233472;    // 1024

  hipMemsetAsync(deg, 0, NN * sizeof(int), stream);

  // FAT A: weight pre-transform + degrank in one launch
  k_preA<<<WCONV_BLOCKS + DEGRANK_BLOCKS, 256, 0, stream>>>(
      Wp, Wl1, Wr1, Wl2, Wr2, W1, W2, wb, ei, deg, rank);

  constexpr int NB = (NN + 255) / 256;
  k_scan1<<<NB, 256, 0, stream>>>(deg, rowst, bsum);
  k_scan2<<<1, 256, 0, stream>>>(bsum, NB);
  k_scan3<<<NB, 256, 0, stream>>>(rowst, bsum);

  // FAT B: mega1 (proj+L1) + scatter in one launch
  k_mainB<<<GX + SCAT_BLOCKS, 512, 0, stream>>>(
      x, Wph, WB1h, bp, bl1, br1, xlh, xrh, NN, ei, rowst, rank, srcp);
  k_gat<<<NN/8, 256, 0, stream>>>(xlh, xrh, srcp, rowst, att1, bias1, h1h);

  // GAT layer 2: fused, M=256, K=128, single pass
  gemm_mfma<0,3,64,1,2><<<dim3(GX, 1), 512, 0, stream>>>(
      h1h, WB2h, bl2, br2, nullptr, xlh, xrh, NN, 256, 128);
  k_gat<<<NN/8, 256, 0, stream>>>(xlh, xrh, srcp, rowst, att2, bias2, h2h);

  // MEGAKERNEL 2: MLP1 + MLP2 -> out
  gemm_mlp<<<GX, 512, 0, stream>>>(h2h, W1h, W2h, b1, b2, out, NN);
}